// Round 1
// baseline (153.279 us; speedup 1.0000x reference)
//
#include <hip/hip_runtime.h>

#define N 4096
#define NUM_BINS 10
#define L (NUM_BINS + 1)   // 11 bin edges
#define SLOTS (2 * L + 1)  // 11 pos + 11 neg + 1 N_pos = 23
#define BLOCK 256

// One block per row. Per-thread private histograms in LDS, laid out
// hist[slot][tid] so the bank index is tid%32 independent of the
// data-dependent slot -> 2 lanes/bank (free on CDNA4, m136).
__global__ __launch_bounds__(BLOCK) void fastap_row_kernel(
    const float* __restrict__ batch, const float* __restrict__ labels,
    float* __restrict__ ap_out, float* __restrict__ valid_out)
{
    __shared__ float hist[SLOTS][BLOCK];  // 23*256*4 = 23.5 KB

    const int tid = threadIdx.x;
    const int row = blockIdx.x;

    #pragma unroll
    for (int s = 0; s < SLOTS - 1; ++s) hist[s][tid] = 0.f;

    const float4* b4 = (const float4*)(batch + (size_t)row * N);
    const float4* l4 = (const float4*)(labels + (size_t)row * N);

    float npos = 0.f;
    #pragma unroll
    for (int it = 0; it < N / (4 * BLOCK); ++it) {  // 4 iterations
        float4 bv = b4[it * BLOCK + tid];
        float4 lv = l4[it * BLOCK + tid];
        #pragma unroll
        for (int e = 0; e < 4; ++e) {
            float x   = ((const float*)&bv)[e];
            float lbl = ((const float*)&lv)[e];
            x = fminf(fmaxf(x, -1.f), 1.f);
            float t = (2.f - 2.f * x) * 2.5f;   // dist2 / Delta, in [0,10]
            int k = (int)t;                     // floor (t >= 0)
            if (k > NUM_BINS) k = NUM_BINS;     // safety at exact 4.0
            float frac = t - (float)k;
            int k2 = k + 1;
            if (k2 > NUM_BINS) k2 = NUM_BINS;   // frac==0 there; add is a no-op
            int base = (lbl > 0.5f) ? 0 : L;    // pos slots 0..10, neg 11..21
            hist[base + k ][tid] += 1.f - frac;
            hist[base + k2][tid] += frac;
            npos += lbl;
        }
    }
    hist[SLOTS - 1][tid] = npos;
    __syncthreads();

    // tree-reduce the 23 slots across 256 threads
    for (int s = BLOCK / 2; s > 0; s >>= 1) {
        if (tid < s) {
            #pragma unroll
            for (int b = 0; b < SLOTS; ++b)
                hist[b][tid] += hist[b][tid + s];
        }
        __syncthreads();
    }

    if (tid == 0) {
        float Hp = 0.f, Hs = 0.f, ap = 0.f;
        #pragma unroll
        for (int l = 0; l < L; ++l) {
            float hp = hist[l][0];
            float hn = hist[L + l][0];
            Hp += hp;
            Hs += hp + hn;
            if (Hs > 0.f) ap += hp * Hp / Hs;
        }
        float Np = hist[SLOTS - 1][0];
        ap_out[row]    = (Np > 0.f) ? ap / Np : 0.f;
        valid_out[row] = (Np > 0.f) ? 1.f : 0.f;
    }
}

__global__ __launch_bounds__(BLOCK) void fastap_reduce_kernel(
    const float* __restrict__ ap, const float* __restrict__ valid,
    float* __restrict__ out)
{
    const int tid = threadIdx.x;
    float s_ap = 0.f, s_v = 0.f;
    for (int i = tid; i < N; i += BLOCK) {
        s_ap += ap[i];
        s_v  += valid[i];
    }
    #pragma unroll
    for (int off = 32; off > 0; off >>= 1) {
        s_ap += __shfl_down(s_ap, off, 64);
        s_v  += __shfl_down(s_v,  off, 64);
    }
    __shared__ float r_ap[BLOCK / 64], r_v[BLOCK / 64];
    const int wave = tid >> 6;
    if ((tid & 63) == 0) { r_ap[wave] = s_ap; r_v[wave] = s_v; }
    __syncthreads();
    if (tid == 0) {
        float ta = 0.f, tv = 0.f;
        #pragma unroll
        for (int w = 0; w < BLOCK / 64; ++w) { ta += r_ap[w]; tv += r_v[w]; }
        out[0] = 1.f - ta / tv;
    }
}

extern "C" void kernel_launch(void* const* d_in, const int* in_sizes, int n_in,
                              void* d_out, int out_size, void* d_ws, size_t ws_size,
                              hipStream_t stream) {
    const float* batch  = (const float*)d_in[0];
    const float* labels = (const float*)d_in[1];
    float* ap    = (float*)d_ws;       // N floats
    float* valid = ap + N;             // N floats
    fastap_row_kernel<<<N, BLOCK, 0, stream>>>(batch, labels, ap, valid);
    fastap_reduce_kernel<<<1, BLOCK, 0, stream>>>(ap, valid, (float*)d_out);
}

// Round 2
// 152.812 us; speedup vs baseline: 1.0031x; 1.0031x over previous
//
#include <hip/hip_runtime.h>

#define N 4096
#define NUM_BINS 10
#define L (NUM_BINS + 1)   // 11 bin edges
#define BLOCK 256
#define WAVES_PER_BLOCK (BLOCK / 64)
#define F4_PER_ROW (N / 4)           // 1024 float4 per row
#define ITERS (F4_PER_ROW / 64)      // 16 float4-iterations per lane

// One WAVE per row; 4 independent waves per block; no LDS, no barriers.
// Branchless soft-binning: all 11 triangular pulses evaluated per element
// into register accumulators (acc_pos[l], acc_all[l]).
// Partition of unity => sum_l h_pos[l] == N_pos, so no separate count.
__global__ __launch_bounds__(BLOCK) void fastap_row_kernel(
    const float* __restrict__ batch, const float* __restrict__ labels,
    float* __restrict__ ap_out, float* __restrict__ valid_out)
{
    const int lane = threadIdx.x & 63;
    const int wave = threadIdx.x >> 6;
    const int row  = blockIdx.x * WAVES_PER_BLOCK + wave;

    const float4* b4 = (const float4*)(batch  + (size_t)row * N);
    const float4* l4 = (const float4*)(labels + (size_t)row * N);

    float acc_pos[L];   // sum of pulse * label
    float acc_all[L];   // sum of pulse (pos + neg)
    #pragma unroll
    for (int l = 0; l < L; ++l) { acc_pos[l] = 0.f; acc_all[l] = 0.f; }

    #pragma unroll 4
    for (int it = 0; it < ITERS; ++it) {
        float4 bv = b4[it * 64 + lane];
        float4 lv = l4[it * 64 + lane];
        #pragma unroll
        for (int e = 0; e < 4; ++e) {
            float x   = ((const float*)&bv)[e];
            float lbl = ((const float*)&lv)[e];
            x = fminf(fmaxf(x, -1.f), 1.f);
            float t = fmaf(-5.f, x, 5.f);       // dist2/Delta = 5 - 5x, in [0,10]
            #pragma unroll
            for (int l = 0; l < L; ++l) {
                float p = fmaxf(0.f, 1.f - fabsf(t - (float)l));  // triangular pulse
                acc_pos[l] = fmaf(p, lbl, acc_pos[l]);
                acc_all[l] += p;
            }
        }
    }

    // butterfly reduce each bin across the 64 lanes (no LDS, no barrier)
    #pragma unroll
    for (int l = 0; l < L; ++l) {
        #pragma unroll
        for (int off = 1; off < 64; off <<= 1) {
            acc_pos[l] += __shfl_xor(acc_pos[l], off, 64);
            acc_all[l] += __shfl_xor(acc_all[l], off, 64);
        }
    }

    if (lane == 0) {
        float Hp = 0.f, Hs = 0.f, ap = 0.f;
        #pragma unroll
        for (int l = 0; l < L; ++l) {
            float hp = acc_pos[l];
            Hp += hp;
            Hs += acc_all[l];
            if (Hs > 0.f) ap += hp * Hp / Hs;
        }
        float Np = Hp;  // partition of unity: sum of h_pos == N_pos
        ap_out[row]    = (Np > 0.f) ? ap / Np : 0.f;
        valid_out[row] = (Np > 0.f) ? 1.f : 0.f;
    }
}

__global__ __launch_bounds__(BLOCK) void fastap_reduce_kernel(
    const float* __restrict__ ap, const float* __restrict__ valid,
    float* __restrict__ out)
{
    const int tid = threadIdx.x;
    float s_ap = 0.f, s_v = 0.f;
    for (int i = tid; i < N; i += BLOCK) {
        s_ap += ap[i];
        s_v  += valid[i];
    }
    #pragma unroll
    for (int off = 32; off > 0; off >>= 1) {
        s_ap += __shfl_down(s_ap, off, 64);
        s_v  += __shfl_down(s_v,  off, 64);
    }
    __shared__ float r_ap[BLOCK / 64], r_v[BLOCK / 64];
    const int wave = tid >> 6;
    if ((tid & 63) == 0) { r_ap[wave] = s_ap; r_v[wave] = s_v; }
    __syncthreads();
    if (tid == 0) {
        float ta = 0.f, tv = 0.f;
        #pragma unroll
        for (int w = 0; w < BLOCK / 64; ++w) { ta += r_ap[w]; tv += r_v[w]; }
        out[0] = 1.f - ta / tv;
    }
}

extern "C" void kernel_launch(void* const* d_in, const int* in_sizes, int n_in,
                              void* d_out, int out_size, void* d_ws, size_t ws_size,
                              hipStream_t stream) {
    const float* batch  = (const float*)d_in[0];
    const float* labels = (const float*)d_in[1];
    float* ap    = (float*)d_ws;       // N floats
    float* valid = ap + N;             // N floats
    fastap_row_kernel<<<N / WAVES_PER_BLOCK, BLOCK, 0, stream>>>(batch, labels, ap, valid);
    fastap_reduce_kernel<<<1, BLOCK, 0, stream>>>(ap, valid, (float*)d_out);
}